// Round 5
// baseline (71.012 us; speedup 1.0000x reference)
//
#include <hip/hip_runtime.h>
#include <hip/hip_bf16.h>

#define EPS 1e-7f
#define LDSW 260   // 256 + 4-float pad; keeps 16B alignment, tiles banks cleanly

typedef __attribute__((ext_vector_type(8))) short short8;
typedef __attribute__((ext_vector_type(4))) float f32x4;

// pack two floats to two bf16 (RNE) in one uint (low = first)
__device__ __forceinline__ unsigned pk(float a, float b) {
    __hip_bfloat162 h2 = __float22bfloat162_rn(make_float2(a, b));
    unsigned r; __builtin_memcpy(&r, &h2, 4); return r;
}

__device__ __forceinline__ short8 mk8(float4 f0, float4 f1) {
    uint4 u;
    u.x = pk(f0.x, f0.y); u.y = pk(f0.z, f0.w);
    u.z = pk(f1.x, f1.y); u.w = pk(f1.z, f1.w);
    short8 r; __builtin_memcpy(&r, &u, 16); return r;
}

// ---------------------------------------------------------------------------
// One fused kernel, 1024 threads (16 waves = 4/SIMD), 1 block/CU.
//   wave w owns m-tile w (m = 16w + lr); 16 batch rows per block.
//   phase 1: issue y-tile load (1 float4/thread = whole tile)
//   phase 2: convert this wave's 8 B-frags from global A (hides y latency)
//   phase 3: ymc = y - c -> LDS, barrier
//   phase 4: 8 s-steps: af from LDS + cf from global c; 2 MFMAs (dot, Ac)
//   phase 5: cand/min (shfl over lr) -> alpha (block-local) -> z epilogue
// ---------------------------------------------------------------------------
__global__ __launch_bounds__(1024, 4)
void fused_kernel(const float* __restrict__ y, const float* __restrict__ A,
                  const float* __restrict__ bb, const float* __restrict__ c,
                  float* __restrict__ z)
{
    __shared__ float ymc[16][LDSW];
    __shared__ float red[16][16];
    __shared__ float alphas[16];

    const int t    = threadIdx.x;
    const int w    = t >> 6;      // wave = m-tile index; also staging row
    const int lane = t & 63;
    const int lr   = lane & 15;   // B-frag col (m) / A-frag row (batch)
    const int lg   = lane >> 4;   // k-group
    const int b0   = blockIdx.x * 16;

    const float4* y4  = (const float4*)y;
    const float4* c4g = (const float4*)c;
    float4* z4 = (float4*)z;

    // phase 1: y-tile load, fully coalesced (1024 float4 = 16 rows x 64)
    const int row  = t >> 6;
    const int col4 = t & 63;
    float4 yv  = y4[(size_t)(b0 + row) * 64 + col4];
    float4 cvs = c4g[col4];

    // phase 2: this wave's B-frags from global A (L2-hot after first blocks)
    const float* arow = A + (size_t)(w * 16 + lr) * 256;
    short8 bf[8];
    #pragma unroll
    for (int s = 0; s < 8; ++s) {
        const float4* ap = (const float4*)(arow + 32 * s + 8 * lg);
        bf[s] = mk8(ap[0], ap[1]);
    }
    const float bmb = bb[w * 16 + lr];

    // phase 3: stage ymc
    float4 r;
    r.x = yv.x - cvs.x; r.y = yv.y - cvs.y;
    r.z = yv.z - cvs.z; r.w = yv.w - cvs.w;
    *(float4*)&ymc[row][col4 * 4] = r;
    __syncthreads();

    // phase 4: MFMA chain (dot = A(y-c), accc = A*c)
    f32x4 acc  = {0.f, 0.f, 0.f, 0.f};
    f32x4 accc = {0.f, 0.f, 0.f, 0.f};
    #pragma unroll
    for (int s = 0; s < 8; ++s) {
        const int col = 32 * s + 8 * lg;
        float4 yv0 = *(const float4*)&ymc[lr][col];
        float4 yv1 = *(const float4*)&ymc[lr][col + 4];
        short8 af = mk8(yv0, yv1);
        float4 cv0 = *(const float4*)(c + col);
        float4 cv1 = *(const float4*)(c + col + 4);
        short8 cf = mk8(cv0, cv1);
        acc  = __builtin_amdgcn_mfma_f32_16x16x32_bf16(af, bf[s], acc,  0, 0, 0);
        accc = __builtin_amdgcn_mfma_f32_16x16x32_bf16(cf, bf[s], accc, 0, 0, 0);
    }

    // phase 5: cand + min over this wave's 16 m (C/D: col=lr, row=4*lg+q)
    const float bm = bmb - accc[0];   // Ac rows identical -> [0] valid for all lg
    float cmin[4];
    #pragma unroll
    for (int q = 0; q < 4; ++q) {
        float ip = bm / (acc[q] + EPS);
        cmin[q] = (ip > 1.f || ip < 0.f) ? 2.f : ip;
    }
    #pragma unroll
    for (int q = 0; q < 4; ++q) {
        float v = cmin[q];
        v = fminf(v, __shfl_xor(v, 1));
        v = fminf(v, __shfl_xor(v, 2));
        v = fminf(v, __shfl_xor(v, 4));
        v = fminf(v, __shfl_xor(v, 8));
        cmin[q] = v;
    }
    if (lr == 0) {
        #pragma unroll
        for (int q = 0; q < 4; ++q) red[w][lg * 4 + q] = cmin[q];
    }
    __syncthreads();

    if (t < 16) {
        float a = red[0][t];
        #pragma unroll
        for (int i = 1; i < 16; ++i) a = fminf(a, red[i][t]);
        alphas[t] = fminf(a, 1.0f);   // alpha > 1 -> 1
    }
    __syncthreads();

    // epilogue: z = c + alpha * (y - c), coalesced (same mapping as staging)
    {
        float al = alphas[row];
        float4 m  = *(const float4*)&ymc[row][col4 * 4];
        float4 o;
        o.x = fmaf(al, m.x, cvs.x);
        o.y = fmaf(al, m.y, cvs.y);
        o.z = fmaf(al, m.z, cvs.z);
        o.w = fmaf(al, m.w, cvs.w);
        z4[(size_t)(b0 + row) * 64 + col4] = o;
    }
}

extern "C" void kernel_launch(void* const* d_in, const int* in_sizes, int n_in,
                              void* d_out, int out_size, void* d_ws, size_t ws_size,
                              hipStream_t stream) {
    const float* y = (const float*)d_in[0];
    const float* A = (const float*)d_in[1];
    const float* b = (const float*)d_in[2];
    const float* c = (const float*)d_in[3];
    float* z = (float*)d_out;

    const int B = in_sizes[0] / 256;    // 4096
    fused_kernel<<<B / 16, 1024, 0, stream>>>(y, A, b, c, z);
}